// Round 16
// baseline (192.250 us; speedup 1.0000x reference)
//
#include <hip/hip_runtime.h>
#include <math.h>

#define SEQ  2048
#define NHD  16
#define HD   64
#define HDIM 1024

typedef short s16x8 __attribute__((ext_vector_type(8)));   // 8 x bf16 (4 VGPRs)
typedef short s16x4 __attribute__((ext_vector_type(4)));
typedef float f32x4 __attribute__((ext_vector_type(4)));

typedef const __attribute__((address_space(1))) unsigned int* gp_t;
typedef __attribute__((address_space(3))) unsigned int* lp_t;

__device__ __forceinline__ void async16(const short* g, short* l) {
    // 16B per lane, LDS dest = wave-uniform base + lane*16 (no per-lane scatter)
    __builtin_amdgcn_global_load_lds((gp_t)g, (lp_t)l, 16, 0, 0);
}

__device__ __forceinline__ short f2bf(float f) {   // RNE f32 -> bf16 bits
    unsigned int u = __float_as_uint(f);
    u += 0x7fff + ((u >> 16) & 1);
    return (short)(u >> 16);
}
__device__ __forceinline__ float bf2f(short s) {
    return __uint_as_float(((unsigned int)(unsigned short)s) << 16);
}
// pack two f32 -> two bf16 (round-half-up; == RNE except exact midpoints):
// one v_perm_b32 grabs both high halves after +0x8000 bias. a -> low short.
__device__ __forceinline__ unsigned pkbf(float a, float b) {
    unsigned ua = __float_as_uint(a) + 0x8000u;
    unsigned ub = __float_as_uint(b) + 0x8000u;
    return __builtin_amdgcn_perm(ua, ub, 0x03020706u);
}

// ---------------- fused: dtype-detect + convert + RoPE table -----------------
#define XG4  (4096 * 1024 / 4)
#define WQG4 (3072 * 1024 / 4)
#define WPG4 (1024 * 1024 / 4)
#define NCVT ((XG4 + WQG4 + WPG4) / 256)
__global__ void cvt_rope_k(const void* __restrict__ xr, const void* __restrict__ wqr,
                           const void* __restrict__ wpr, short* __restrict__ xo,
                           short* __restrict__ wqo, short* __restrict__ wpo,
                           float2* __restrict__ tab) {
    const int tid = threadIdx.x;
    if (blockIdx.x >= NCVT) {                  // RoPE-table tail blocks
        int i = (blockIdx.x - NCVT) * 256 + tid;
        int s = i >> 5, d = i & 31;
        float invf = (float)pow(10000.0, -(double)d / 32.0);
        float af = (float)s * invf;            // replicate f32 freqs product
        tab[i] = make_float2((float)cos((double)af), (float)sin((double)af));
        return;
    }
    int i = blockIdx.x * 256 + tid;
    const void* in; short* out; int j;
    if (i < XG4)             { in = xr;  out = xo;  j = i; }
    else if (i < XG4 + WQG4) { in = wqr; out = wqo; j = i - XG4; }
    else                     { in = wpr; out = wpo; j = i - XG4 - WQG4; }
    // per-block dtype vote: sample 256 u16 from this block's own span
    const int jbase = j - tid;
    unsigned short h = ((const unsigned short*)in)[(size_t)jbase * 4 + tid];
    int e = (h >> 7) & 0xFF;
    unsigned long long b = __ballot(e >= 100 && e <= 140);
    __shared__ int tot;
    if (tid == 0) tot = 0;
    __syncthreads();
    if ((tid & 63) == 0) atomicAdd(&tot, __popcll(b));
    __syncthreads();
    if (tot > 230) {                           // bf16: straight copy
        ((s16x4*)out)[j] = ((const s16x4*)in)[j];
    } else {                                   // f32 -> bf16
        f32x4 v = ((const f32x4*)in)[j];
        union { unsigned u[2]; s16x4 v; } r;
        r.u[0] = pkbf(v[0], v[1]);
        r.u[1] = pkbf(v[2], v[3]);
        ((s16x4*)out)[j] = r.v;
    }
}

// ---------------- 128x128 bf16 MFMA GEMM (qkv): B given as [N,K] -------------
// Double-buffered single-barrier K-loop. LDS rows = 4 x 16B chunks, slot
// c^(r&3). qkv epilogue via per-wave 8KB LDS arena -> coalesced 16B stores
// for q,k (RoPE'd, q scaled log2e/8) AND v^T.
__global__ __launch_bounds__(256, 2)
void gemm_qkv(const short* __restrict__ A, const short* __restrict__ B,
              short* __restrict__ q, short* __restrict__ kbuf, short* __restrict__ vt,
              const float2* __restrict__ tab, int K) {
    __shared__ __align__(16) short As[2][128 * 32];
    __shared__ __align__(16) short Bs[2][128 * 32];
    const int tid  = threadIdx.x;
    const int w    = tid >> 6, lane = tid & 63;
    const int quad = lane >> 4, l16 = lane & 15;
    const int wm = (w >> 1) * 64, wn = (w & 1) * 64;
    const int rowA0 = blockIdx.y * 128;
    const int colB0 = blockIdx.x * 128;

    auto stage = [&](int buf, int kb) {
        #pragma unroll
        for (int i = 0; i < 2; ++i) {
            int cidx = i * 256 + w * 64 + lane;
            int row = cidx >> 2, sc = cidx & 3;
            int c = sc ^ (row & 3);           // XOR swizzle
            async16(&A[(long)(rowA0 + row) * K + kb + c * 8],
                    &As[buf][(i * 256 + w * 64) * 8]);
            async16(&B[(long)(colB0 + row) * K + kb + c * 8],
                    &Bs[buf][(i * 256 + w * 64) * 8]);
        }
    };

    f32x4 acc[4][4] = {};
    stage(0, 0);

    for (int kb = 0, it = 0; kb < K; kb += 32, ++it) {
        const int cur = it & 1;
        __syncthreads();                      // drains cur's loads; prev readers done
        if (kb + 32 < K) stage(cur ^ 1, kb + 32);

        s16x8 af[4], bfr[4];
        const int slot = quad ^ (l16 & 3);
        #pragma unroll
        for (int mi = 0; mi < 4; ++mi)
            af[mi] = *(const s16x8*)&As[cur][(wm + mi * 16 + l16) * 32 + slot * 8];
        #pragma unroll
        for (int ni = 0; ni < 4; ++ni)
            bfr[ni] = *(const s16x8*)&Bs[cur][(wn + ni * 16 + l16) * 32 + slot * 8];
        #pragma unroll
        for (int mi = 0; mi < 4; ++mi)
            #pragma unroll
            for (int ni = 0; ni < 4; ++ni)
                acc[mi][ni] = __builtin_amdgcn_mfma_f32_16x16x32_bf16(
                    af[mi], bfr[ni], acc[mi][ni], 0, 0, 0);
    }

    const int cb = colB0 + wn;                // wave's 64-col (one head) window
    const int sector = cb >> 10;              // 0=q 1=k 2=v (block-uniform)
    const int head   = (cb & 1023) >> 6;
    const int gmb = rowA0 + wm;
    const int b = gmb >> 11, s0 = gmb & 2047;
    __syncthreads();                          // all waves done with As/Bs frags
    short* arena = (w < 2) ? (&As[0][0] + w * 4096) : (&Bs[0][0] + (w - 2) * 4096);
    auto aw = [&](int row, int col, short val) {
        arena[row * 64 + (((col >> 3) ^ (row & 7)) << 3) + (col & 7)] = val;
    };
    if (sector < 2) {
        // q gets 1/8 (attn scale) * log2(e) (exp2-domain softmax) folded in
        const float sc = (sector == 0) ? 0.18033688f : 1.0f;
        #pragma unroll
        for (int mi = 0; mi < 4; ++mi) {
            #pragma unroll
            for (int r = 0; r < 4; ++r) {
                int lrow = mi * 16 + quad * 4 + r;
                int s = s0 + lrow;
                float v0 = acc[mi][0][r], v1 = acc[mi][1][r];
                float v2 = acc[mi][2][r], v3 = acc[mi][3][r];
                // RoPE d<32: d0=l16, d1=l16+16; rot(d0)=-x[d0+16], rot(d1)=x[d1-16]
                float2 cs0 = tab[s * 32 + l16];
                float2 cs1 = tab[s * 32 + 16 + l16];
                float n0 = v0 * cs0.x - v1 * cs0.y;
                float n1 = v1 * cs1.x + v0 * cs1.y;
                aw(lrow, l16,      f2bf(n0 * sc));
                aw(lrow, l16 + 16, f2bf(n1 * sc));
                aw(lrow, l16 + 32, f2bf(v2 * sc));
                aw(lrow, l16 + 48, f2bf(v3 * sc));
            }
        }
        short* dst0 = (sector == 0 ? q : kbuf)
                    + ((long)((b * NHD + head) * SEQ + s0)) * HD;
        #pragma unroll
        for (int it = 0; it < 8; ++it) {      // 64 rows x 128B, coalesced out
            int row = it * 8 + (lane >> 3), cc = lane & 7;
            s16x8 vv = *(const s16x8*)&arena[row * 64 + ((cc ^ (row & 7)) << 3)];
            *(s16x8*)&dst0[row * HD + cc * 8] = vv;
        }
    } else {
        // arena transposed: [row=d][col=s_local]; out = contiguous vt rows
        #pragma unroll
        for (int mi = 0; mi < 4; ++mi) {
            #pragma unroll
            for (int r = 0; r < 4; ++r) {
                int scol = mi * 16 + quad * 4 + r;
                aw(l16,      scol, f2bf(acc[mi][0][r]));
                aw(l16 + 16, scol, f2bf(acc[mi][1][r]));
                aw(l16 + 32, scol, f2bf(acc[mi][2][r]));
                aw(l16 + 48, scol, f2bf(acc[mi][3][r]));
            }
        }
        short* dstv = vt + ((long)((b * NHD + head) * HD)) * SEQ + s0;
        #pragma unroll
        for (int it = 0; it < 8; ++it) {      // 64 d-rows x 128B contiguous
            int dd = it * 8 + (lane >> 3), so8 = lane & 7;
            s16x8 vv = *(const s16x8*)&arena[dd * 64 + ((so8 ^ (dd & 7)) << 3)];
            *(s16x8*)&dstv[(long)dd * SEQ + so8 * 8] = vv;
        }
    }
}

// ---------------- flash attention v9: raw v_exp, no per-iter acc zeroing -----
__global__ __launch_bounds__(256, 4)
void flash_attn(const short* __restrict__ Q, const short* __restrict__ K,
                const short* __restrict__ Vt, short* __restrict__ opart,
                float* __restrict__ lpart, int nt) {
    __shared__ __align__(16) short Ks[2][64 * 64];
    __shared__ __align__(16) short Vs[2][64 * 64];   // V^T: rows=d, cols=key
    const int tid  = threadIdx.x;
    const int w    = tid >> 6, lane = tid & 63;
    const int quad = lane >> 4, l16 = lane & 15;
    const int bh = blockIdx.x >> 1;             // (bh,z) fastest -> XCD-local
    const int z  = blockIdx.x & 1;
    const int qb = blockIdx.y * 128;
    const short* Qp = Q  + (long)bh * SEQ * HD + (long)qb * HD;
    const short* Kp = K  + (long)bh * SEQ * HD;
    const short* Vp = Vt + (long)bh * HD * SEQ;
    const int kt0 = z * nt;

    auto stage = [&](int buf, int kt) {
        #pragma unroll
        for (int i = 0; i < 2; ++i) {
            int cidx = i * 256 + w * 64 + lane;
            int row = cidx >> 3, sc = cidx & 7;
            int c = sc ^ (row & 7);
            async16(&Kp[(kt * 64 + row) * HD + c * 8],
                    &Ks[buf][(i * 256 + w * 64) * 8]);
            async16(&Vp[(long)row * SEQ + kt * 64 + c * 8],
                    &Vs[buf][(i * 256 + w * 64) * 8]);
        }
    };

    s16x8 aq[2][2];                             // B-operand: qrow, k=quad*8+j
    #pragma unroll
    for (int mi = 0; mi < 2; ++mi)
        #pragma unroll
        for (int ks = 0; ks < 2; ++ks)
            aq[mi][ks] = *(const s16x8*)&Qp[(w * 32 + mi * 16 + l16) * HD
                                            + ks * 32 + quad * 8];

    s16x8 ones8;
    #pragma unroll
    for (int j = 0; j < 8; ++j) ones8[j] = (short)0x3F80;  // bf16 1.0

    const f32x4 z4 = {};                        // persistent zero C-operand
    f32x4 oacc[2][4] = {};
    f32x4 lacc[2] = {};

    stage(0, kt0);
    for (int it = 0; it < nt; ++it) {
        const int cur = it & 1;
        __syncthreads();                        // drains cur's loads; prev readers done
        if (it + 1 < nt) stage(cur ^ 1, kt0 + it + 1);
        const short* kcur = Ks[cur];
        const short* vcur = Vs[cur];

        // S^T = K·Q^T : st[mi][ki] = tile [key=ki*16+quad*4+r][qrow]
        f32x4 st[2][4];
        #pragma unroll
        for (int ki = 0; ki < 4; ++ki) {
            s16x8 ak0 = *(const s16x8*)&kcur[(ki * 16 + l16) * 64 + (quad ^ (l16 & 7)) * 8];
            s16x8 ak1 = *(const s16x8*)&kcur[(ki * 16 + l16) * 64 + ((4 + quad) ^ (l16 & 7)) * 8];
            #pragma unroll
            for (int mi = 0; mi < 2; ++mi) {
                st[mi][ki] = __builtin_amdgcn_mfma_f32_16x16x32_bf16(
                    ak0, aq[mi][0], z4, 0, 0, 0);
                st[mi][ki] = __builtin_amdgcn_mfma_f32_16x16x32_bf16(
                    ak1, aq[mi][1], st[mi][ki], 0, 0, 0);
            }
        }

        // P = exp2(st) via raw v_exp_f32; pkbf-pack pairs for dense-K PV MFMA
        s16x8 bp[2][2];
        #pragma unroll
        for (int mi = 0; mi < 2; ++mi)
            #pragma unroll
            for (int t = 0; t < 2; ++t) {
                union { unsigned u[4]; s16x8 v; } pk;
                pk.u[0] = pkbf(__builtin_amdgcn_exp2f(st[mi][2 * t][0]),
                               __builtin_amdgcn_exp2f(st[mi][2 * t][1]));
                pk.u[1] = pkbf(__builtin_amdgcn_exp2f(st[mi][2 * t][2]),
                               __builtin_amdgcn_exp2f(st[mi][2 * t][3]));
                pk.u[2] = pkbf(__builtin_amdgcn_exp2f(st[mi][2 * t + 1][0]),
                               __builtin_amdgcn_exp2f(st[mi][2 * t + 1][1]));
                pk.u[3] = pkbf(__builtin_amdgcn_exp2f(st[mi][2 * t + 1][2]),
                               __builtin_amdgcn_exp2f(st[mi][2 * t + 1][3]));
                bp[mi][t] = pk.v;
            }

        // O += P·V ; l += P·1  (virtual k: j<4 -> key 32t+quad*4+j,
        //                                  j>=4 -> key 32t+16+quad*4+j-4)
        #pragma unroll
        for (int t = 0; t < 2; ++t) {
            #pragma unroll
            for (int nd = 0; nd < 4; ++nd) {
                int d = nd * 16 + l16;
                s16x4 va = *(const s16x4*)&vcur[d * 64
                             + ((4 * t + (quad >> 1)) ^ (l16 & 7)) * 8
                             + (quad & 1) * 4];
                s16x4 vb = *(const s16x4*)&vcur[d * 64
                             + ((4 * t + 2 + (quad >> 1)) ^ (l16 & 7)) * 8
                             + (quad & 1) * 4];
                s16x8 av = {va[0], va[1], va[2], va[3],
                            vb[0], vb[1], vb[2], vb[3]};
                #pragma unroll
                for (int mi = 0; mi < 2; ++mi)
                    oacc[mi][nd] = __builtin_amdgcn_mfma_f32_16x16x32_bf16(
                        av, bp[mi][t], oacc[mi][nd], 0, 0, 0);
            }
            #pragma unroll
            for (int mi = 0; mi < 2; ++mi)
                lacc[mi] = __builtin_amdgcn_mfma_f32_16x16x32_bf16(
                    ones8, bp[mi][t], lacc[mi], 0, 0, 0);
        }
    }

    // partial store: unnormalized O (bf16, pkbf-packed) + l per row
    #pragma unroll
    for (int mi = 0; mi < 2; ++mi) {
        int srow = qb + w * 32 + mi * 16 + l16;
        long prow = (long)(z * 2 * NHD + bh) * SEQ + srow;
        if (quad == 0) lpart[prow] = lacc[mi][0];
        short* op = opart + prow * 64 + quad * 4;
        #pragma unroll
        for (int nd = 0; nd < 4; ++nd) {
            union { unsigned u[2]; s16x4 v; } pk;
            pk.u[0] = pkbf(oacc[mi][nd][0], oacc[mi][nd][1]);
            pk.u[1] = pkbf(oacc[mi][nd][2], oacc[mi][nd][3]);
            *(s16x4*)&op[nd * 16] = pk.v;
        }
    }
}

// ---------------- projection GEMM with FUSED split-K merge -------------------
// out[gm][n] = sum_col att[gm][col] * Wproj[n][col], where att is computed
// on the fly from opart/lpart: att[(b,s)][h*64+d] = (o1+o2)*inv.
// 64x128 tile (grid 8x64 = 512 blocks = 2/CU). A staged via registers
// (inline merge) + ds_write_b128; B (wprj) staged via async16. Double-buffered.
__global__ __launch_bounds__(256, 2)
void gemm_proj(const short* __restrict__ opart, const float* __restrict__ lpart,
               const short* __restrict__ B, float* __restrict__ C) {
    __shared__ __align__(16) short As[2][64 * 32];
    __shared__ __align__(16) short Bs[2][128 * 32];
    const int tid  = threadIdx.x;
    const int w    = tid >> 6, lane = tid & 63;
    const int quad = lane >> 4, l16 = lane & 15;
    const int wm = (w >> 1) * 32, wn = (w & 1) * 64;
    const int rowA0 = blockIdx.y * 64;
    const int colB0 = blockIdx.x * 128;

    auto stageB = [&](int buf, int kb) {
        #pragma unroll
        for (int i = 0; i < 2; ++i) {
            int cidx = i * 256 + w * 64 + lane;
            int row = cidx >> 2, sc = cidx & 3;
            int c = sc ^ (row & 3);
            async16(&B[(long)(colB0 + row) * HDIM + kb + c * 8],
                    &Bs[buf][(i * 256 + w * 64) * 8]);
        }
    };
    auto stageA = [&](int buf, int kb) {      // 256 chunks, 1/thread, inline merge
        int cidx = w * 64 + lane;
        int row = cidx >> 2, sc = cidx & 3;
        int c = sc ^ (row & 3);
        int col = kb + c * 8;                 // k-col: h = col>>6, d = col&63
        int h = col >> 6, d = col & 63;
        int gm = rowA0 + row;
        int b = gm >> 11, s = gm & 2047;
        long prow = (long)(b * NHD + h) * SEQ + s;
        s16x8 o1 = *(const s16x8*)&opart[prow * 64 + d];
        s16x8 o2 = *(const s16x8*)&opart[(prow + 65536) * 64 + d];
        float inv = 1.0f / (lpart[prow] + lpart[prow + 65536]);
        union { unsigned u[4]; s16x8 v; } pk;
        #pragma unroll
        for (int j = 0; j < 4; ++j)
            pk.u[j] = pkbf((bf2f(o1[2 * j])     + bf2f(o2[2 * j]))     * inv,
                           (bf2f(o1[2 * j + 1]) + bf2f(o2[2 * j + 1])) * inv);
        *(s16x8*)&As[buf][(row * 4 + sc) * 8] = pk.v;
    };

    f32x4 acc[2][4] = {};
    stageB(0, 0);
    stageA(0, 0);

    for (int kb = 0, it = 0; kb < HDIM; kb += 32, ++it) {
        const int cur = it & 1;
        __syncthreads();                      // drains cur's loads; prev readers done
        if (kb + 32 < HDIM) { stageB(cur ^ 1, kb + 32); stageA(cur ^ 1, kb + 32); }

        s16x8 af[2], bfr[4];
        const int slot = quad ^ (l16 & 3);
        #pragma unroll
        for (int mi = 0; mi < 2; ++mi)
            af[mi] = *(const s16x8*)&As[cur][(wm + mi * 16 + l16) * 32 + slot * 8];
        #pragma unroll
        for (int ni = 0; ni < 4; ++ni)
            bfr[ni] = *(const s16x8*)&Bs[cur][(wn + ni * 16 + l16) * 32 + slot * 8];
        #pragma unroll
        for (int mi = 0; mi < 2; ++mi)
            #pragma unroll
            for (int ni = 0; ni < 4; ++ni)
                acc[mi][ni] = __builtin_amdgcn_mfma_f32_16x16x32_bf16(
                    af[mi], bfr[ni], acc[mi][ni], 0, 0, 0);
    }

    const int cb = colB0 + wn;
    #pragma unroll
    for (int mi = 0; mi < 2; ++mi) {
        #pragma unroll
        for (int r = 0; r < 4; ++r) {
            int gm = rowA0 + wm + mi * 16 + quad * 4 + r;
            float* cp = C + (long)gm * HDIM + cb + l16;
            #pragma unroll
            for (int ni = 0; ni < 4; ++ni)
                cp[ni * 16] = acc[mi][ni][r];
        }
    }
}

extern "C" void kernel_launch(void* const* d_in, const int* in_sizes, int n_in,
                              void* d_out, int out_size, void* d_ws, size_t ws_size,
                              hipStream_t stream) {
    const void* x_raw  = d_in[0];
    const void* Wq_raw = d_in[1];
    const void* Wp_raw = d_in[2];
    for (int i = 0; i < n_in; ++i) {
        if      (in_sizes[i] == 4096 * 1024) x_raw  = d_in[i];  // [2,2048,1024]
        else if (in_sizes[i] == 3072 * 1024) Wq_raw = d_in[i];  // [3072,1024]
        else if (in_sizes[i] == 1024 * 1024) Wp_raw = d_in[i];  // [1024,1024]
    }
    float* out = (float*)d_out;               // [2,2048,1024] f32 output

    const size_t MB = 1u << 20;
    char* ws = (char*)d_ws;
    short*  q     = (short*)(ws);             // [2,16,2048,64]  8 MB (scaled)
    short*  k     = (short*)(ws +  8 * MB);   // [2,16,2048,64]  8 MB
    short*  vt    = (short*)(ws + 16 * MB);   // [2,16,64,2048]  8 MB (V^T)
    short*  xbf   = (short*)(ws + 24 * MB);   // [4096,1024]     8 MB
    short*  wqkv  = (short*)(ws + 32 * MB);   // [3072,1024]     6 MB
    short*  wprj  = (short*)(ws + 38 * MB);   // [1024,1024]     2 MB
    float2* tab   = (float2*)(ws + 40 * MB);  // [2048,32]       512 KB
    short*  opart = (short*)(ws + 41 * MB);   // 2 x [2,16,2048,64] 16 MB bf16
    float*  lprt  = (float*)(ws + 57 * MB);   // 2 x [2,16,2048]  512 KB

    cvt_rope_k<<<dim3(NCVT + SEQ * 32 / 256), dim3(256), 0, stream>>>(
        x_raw, Wq_raw, Wp_raw, xbf, wqkv, wprj, tab);

    gemm_qkv<<<dim3(3072 / 128, 4096 / 128), dim3(256), 0, stream>>>(
        xbf, wqkv, q, k, vt, tab, 1024);

    flash_attn<<<dim3(2 * NHD * 2, SEQ / 128), dim3(256), 0, stream>>>(
        q, k, vt, opart, lprt, 16);

    gemm_proj<<<dim3(1024 / 128, 4096 / 64), dim3(256), 0, stream>>>(
        opart, lprt, wprj, out);
}

// Round 17
// 187.837 us; speedup vs baseline: 1.0235x; 1.0235x over previous
//
#include <hip/hip_runtime.h>
#include <math.h>

#define SEQ  2048
#define NHD  16
#define HD   64
#define HDIM 1024

typedef short s16x8 __attribute__((ext_vector_type(8)));   // 8 x bf16 (4 VGPRs)
typedef short s16x4 __attribute__((ext_vector_type(4)));
typedef float f32x4 __attribute__((ext_vector_type(4)));

typedef const __attribute__((address_space(1))) unsigned int* gp_t;
typedef __attribute__((address_space(3))) unsigned int* lp_t;

__device__ __forceinline__ void async16(const short* g, short* l) {
    // 16B per lane, LDS dest = wave-uniform base + lane*16 (no per-lane scatter)
    __builtin_amdgcn_global_load_lds((gp_t)g, (lp_t)l, 16, 0, 0);
}

__device__ __forceinline__ short f2bf(float f) {   // RNE f32 -> bf16 bits
    unsigned int u = __float_as_uint(f);
    u += 0x7fff + ((u >> 16) & 1);
    return (short)(u >> 16);
}
__device__ __forceinline__ float bf2f(short s) {
    return __uint_as_float(((unsigned int)(unsigned short)s) << 16);
}
// pack two f32 -> two bf16 (round-half-up; == RNE except exact midpoints):
// one v_perm_b32 grabs both high halves after +0x8000 bias. a -> low short.
__device__ __forceinline__ unsigned pkbf(float a, float b) {
    unsigned ua = __float_as_uint(a) + 0x8000u;
    unsigned ub = __float_as_uint(b) + 0x8000u;
    return __builtin_amdgcn_perm(ua, ub, 0x03020706u);
}

// ---------------- fused: dtype-detect + convert + RoPE table -----------------
#define XG4  (4096 * 1024 / 4)
#define WQG4 (3072 * 1024 / 4)
#define WPG4 (1024 * 1024 / 4)
#define NCVT ((XG4 + WQG4 + WPG4) / 256)
__global__ void cvt_rope_k(const void* __restrict__ xr, const void* __restrict__ wqr,
                           const void* __restrict__ wpr, short* __restrict__ xo,
                           short* __restrict__ wqo, short* __restrict__ wpo,
                           float2* __restrict__ tab) {
    const int tid = threadIdx.x;
    if (blockIdx.x >= NCVT) {                  // RoPE-table tail blocks
        int i = (blockIdx.x - NCVT) * 256 + tid;
        int s = i >> 5, d = i & 31;
        float invf = (float)pow(10000.0, -(double)d / 32.0);
        float af = (float)s * invf;            // replicate f32 freqs product
        tab[i] = make_float2((float)cos((double)af), (float)sin((double)af));
        return;
    }
    int i = blockIdx.x * 256 + tid;
    const void* in; short* out; int j;
    if (i < XG4)             { in = xr;  out = xo;  j = i; }
    else if (i < XG4 + WQG4) { in = wqr; out = wqo; j = i - XG4; }
    else                     { in = wpr; out = wpo; j = i - XG4 - WPG4 - WQG4 + WPG4; }
    if (i >= XG4 + WQG4) j = i - XG4 - WQG4;
    // per-block dtype vote: sample 256 u16 from this block's own span
    const int jbase = j - tid;
    unsigned short h = ((const unsigned short*)in)[(size_t)jbase * 4 + tid];
    int e = (h >> 7) & 0xFF;
    unsigned long long b = __ballot(e >= 100 && e <= 140);
    __shared__ int tot;
    if (tid == 0) tot = 0;
    __syncthreads();
    if ((tid & 63) == 0) atomicAdd(&tot, __popcll(b));
    __syncthreads();
    if (tot > 230) {                           // bf16: straight copy
        ((s16x4*)out)[j] = ((const s16x4*)in)[j];
    } else {                                   // f32 -> bf16
        f32x4 v = ((const f32x4*)in)[j];
        union { unsigned u[2]; s16x4 v; } r;
        r.u[0] = pkbf(v[0], v[1]);
        r.u[1] = pkbf(v[2], v[3]);
        ((s16x4*)out)[j] = r.v;
    }
}

// ---------------- 128x128 bf16 MFMA GEMM (qkv): B given as [N,K] -------------
// Double-buffered single-barrier K-loop. LDS rows = 4 x 16B chunks, slot
// c^(r&3). qkv epilogue via per-wave 8KB LDS arena -> coalesced 16B stores
// for q,k (RoPE'd, q scaled log2e/8) AND v^T.
__global__ __launch_bounds__(256, 2)
void gemm_qkv(const short* __restrict__ A, const short* __restrict__ B,
              short* __restrict__ q, short* __restrict__ kbuf, short* __restrict__ vt,
              const float2* __restrict__ tab, int K) {
    __shared__ __align__(16) short As[2][128 * 32];
    __shared__ __align__(16) short Bs[2][128 * 32];
    const int tid  = threadIdx.x;
    const int w    = tid >> 6, lane = tid & 63;
    const int quad = lane >> 4, l16 = lane & 15;
    const int wm = (w >> 1) * 64, wn = (w & 1) * 64;
    const int rowA0 = blockIdx.y * 128;
    const int colB0 = blockIdx.x * 128;

    auto stage = [&](int buf, int kb) {
        #pragma unroll
        for (int i = 0; i < 2; ++i) {
            int cidx = i * 256 + w * 64 + lane;
            int row = cidx >> 2, sc = cidx & 3;
            int c = sc ^ (row & 3);           // XOR swizzle
            async16(&A[(long)(rowA0 + row) * K + kb + c * 8],
                    &As[buf][(i * 256 + w * 64) * 8]);
            async16(&B[(long)(colB0 + row) * K + kb + c * 8],
                    &Bs[buf][(i * 256 + w * 64) * 8]);
        }
    };

    f32x4 acc[4][4] = {};
    stage(0, 0);

    for (int kb = 0, it = 0; kb < K; kb += 32, ++it) {
        const int cur = it & 1;
        __syncthreads();                      // drains cur's loads; prev readers done
        if (kb + 32 < K) stage(cur ^ 1, kb + 32);

        s16x8 af[4], bfr[4];
        const int slot = quad ^ (l16 & 3);
        #pragma unroll
        for (int mi = 0; mi < 4; ++mi)
            af[mi] = *(const s16x8*)&As[cur][(wm + mi * 16 + l16) * 32 + slot * 8];
        #pragma unroll
        for (int ni = 0; ni < 4; ++ni)
            bfr[ni] = *(const s16x8*)&Bs[cur][(wn + ni * 16 + l16) * 32 + slot * 8];
        #pragma unroll
        for (int mi = 0; mi < 4; ++mi)
            #pragma unroll
            for (int ni = 0; ni < 4; ++ni)
                acc[mi][ni] = __builtin_amdgcn_mfma_f32_16x16x32_bf16(
                    af[mi], bfr[ni], acc[mi][ni], 0, 0, 0);
    }

    const int cb = colB0 + wn;                // wave's 64-col (one head) window
    const int sector = cb >> 10;              // 0=q 1=k 2=v (block-uniform)
    const int head   = (cb & 1023) >> 6;
    const int gmb = rowA0 + wm;
    const int b = gmb >> 11, s0 = gmb & 2047;
    __syncthreads();                          // all waves done with As/Bs frags
    short* arena = (w < 2) ? (&As[0][0] + w * 4096) : (&Bs[0][0] + (w - 2) * 4096);
    auto aw = [&](int row, int col, short val) {
        arena[row * 64 + (((col >> 3) ^ (row & 7)) << 3) + (col & 7)] = val;
    };
    if (sector < 2) {
        // q gets 1/8 (attn scale) * log2(e) (exp2-domain softmax) folded in
        const float sc = (sector == 0) ? 0.18033688f : 1.0f;
        #pragma unroll
        for (int mi = 0; mi < 4; ++mi) {
            #pragma unroll
            for (int r = 0; r < 4; ++r) {
                int lrow = mi * 16 + quad * 4 + r;
                int s = s0 + lrow;
                float v0 = acc[mi][0][r], v1 = acc[mi][1][r];
                float v2 = acc[mi][2][r], v3 = acc[mi][3][r];
                // RoPE d<32: d0=l16, d1=l16+16; rot(d0)=-x[d0+16], rot(d1)=x[d1-16]
                float2 cs0 = tab[s * 32 + l16];
                float2 cs1 = tab[s * 32 + 16 + l16];
                float n0 = v0 * cs0.x - v1 * cs0.y;
                float n1 = v1 * cs1.x + v0 * cs1.y;
                aw(lrow, l16,      f2bf(n0 * sc));
                aw(lrow, l16 + 16, f2bf(n1 * sc));
                aw(lrow, l16 + 32, f2bf(v2 * sc));
                aw(lrow, l16 + 48, f2bf(v3 * sc));
            }
        }
        short* dst0 = (sector == 0 ? q : kbuf)
                    + ((long)((b * NHD + head) * SEQ + s0)) * HD;
        #pragma unroll
        for (int it = 0; it < 8; ++it) {      // 64 rows x 128B, coalesced out
            int row = it * 8 + (lane >> 3), cc = lane & 7;
            s16x8 vv = *(const s16x8*)&arena[row * 64 + ((cc ^ (row & 7)) << 3)];
            *(s16x8*)&dst0[row * HD + cc * 8] = vv;
        }
    } else {
        // arena transposed: [row=d][col=s_local]; out = contiguous vt rows
        #pragma unroll
        for (int mi = 0; mi < 4; ++mi) {
            #pragma unroll
            for (int r = 0; r < 4; ++r) {
                int scol = mi * 16 + quad * 4 + r;
                aw(l16,      scol, f2bf(acc[mi][0][r]));
                aw(l16 + 16, scol, f2bf(acc[mi][1][r]));
                aw(l16 + 32, scol, f2bf(acc[mi][2][r]));
                aw(l16 + 48, scol, f2bf(acc[mi][3][r]));
            }
        }
        short* dstv = vt + ((long)((b * NHD + head) * HD)) * SEQ + s0;
        #pragma unroll
        for (int it = 0; it < 8; ++it) {      // 64 d-rows x 128B contiguous
            int dd = it * 8 + (lane >> 3), so8 = lane & 7;
            s16x8 vv = *(const s16x8*)&arena[dd * 64 + ((so8 ^ (dd & 7)) << 3)];
            *(s16x8*)&dstv[(long)dd * SEQ + so8 * 8] = vv;
        }
    }
}

// ---------------- flash attention v9: raw v_exp, no per-iter acc zeroing -----
__global__ __launch_bounds__(256, 4)
void flash_attn(const short* __restrict__ Q, const short* __restrict__ K,
                const short* __restrict__ Vt, short* __restrict__ opart,
                float* __restrict__ lpart, int nt) {
    __shared__ __align__(16) short Ks[2][64 * 64];
    __shared__ __align__(16) short Vs[2][64 * 64];   // V^T: rows=d, cols=key
    const int tid  = threadIdx.x;
    const int w    = tid >> 6, lane = tid & 63;
    const int quad = lane >> 4, l16 = lane & 15;
    const int bh = blockIdx.x >> 1;             // (bh,z) fastest -> XCD-local
    const int z  = blockIdx.x & 1;
    const int qb = blockIdx.y * 128;
    const short* Qp = Q  + (long)bh * SEQ * HD + (long)qb * HD;
    const short* Kp = K  + (long)bh * SEQ * HD;
    const short* Vp = Vt + (long)bh * HD * SEQ;
    const int kt0 = z * nt;

    auto stage = [&](int buf, int kt) {
        #pragma unroll
        for (int i = 0; i < 2; ++i) {
            int cidx = i * 256 + w * 64 + lane;
            int row = cidx >> 3, sc = cidx & 7;
            int c = sc ^ (row & 7);
            async16(&Kp[(kt * 64 + row) * HD + c * 8],
                    &Ks[buf][(i * 256 + w * 64) * 8]);
            async16(&Vp[(long)row * SEQ + kt * 64 + c * 8],
                    &Vs[buf][(i * 256 + w * 64) * 8]);
        }
    };

    s16x8 aq[2][2];                             // B-operand: qrow, k=quad*8+j
    #pragma unroll
    for (int mi = 0; mi < 2; ++mi)
        #pragma unroll
        for (int ks = 0; ks < 2; ++ks)
            aq[mi][ks] = *(const s16x8*)&Qp[(w * 32 + mi * 16 + l16) * HD
                                            + ks * 32 + quad * 8];

    s16x8 ones8;
    #pragma unroll
    for (int j = 0; j < 8; ++j) ones8[j] = (short)0x3F80;  // bf16 1.0

    const f32x4 z4 = {};                        // persistent zero C-operand
    f32x4 oacc[2][4] = {};
    f32x4 lacc[2] = {};

    stage(0, kt0);
    for (int it = 0; it < nt; ++it) {
        const int cur = it & 1;
        __syncthreads();                        // drains cur's loads; prev readers done
        if (it + 1 < nt) stage(cur ^ 1, kt0 + it + 1);
        const short* kcur = Ks[cur];
        const short* vcur = Vs[cur];

        // S^T = K·Q^T : st[mi][ki] = tile [key=ki*16+quad*4+r][qrow]
        f32x4 st[2][4];
        #pragma unroll
        for (int ki = 0; ki < 4; ++ki) {
            s16x8 ak0 = *(const s16x8*)&kcur[(ki * 16 + l16) * 64 + (quad ^ (l16 & 7)) * 8];
            s16x8 ak1 = *(const s16x8*)&kcur[(ki * 16 + l16) * 64 + ((4 + quad) ^ (l16 & 7)) * 8];
            #pragma unroll
            for (int mi = 0; mi < 2; ++mi) {
                st[mi][ki] = __builtin_amdgcn_mfma_f32_16x16x32_bf16(
                    ak0, aq[mi][0], z4, 0, 0, 0);
                st[mi][ki] = __builtin_amdgcn_mfma_f32_16x16x32_bf16(
                    ak1, aq[mi][1], st[mi][ki], 0, 0, 0);
            }
        }

        // P = exp2(st) via raw v_exp_f32; pkbf-pack pairs for dense-K PV MFMA
        s16x8 bp[2][2];
        #pragma unroll
        for (int mi = 0; mi < 2; ++mi)
            #pragma unroll
            for (int t = 0; t < 2; ++t) {
                union { unsigned u[4]; s16x8 v; } pk;
                pk.u[0] = pkbf(__builtin_amdgcn_exp2f(st[mi][2 * t][0]),
                               __builtin_amdgcn_exp2f(st[mi][2 * t][1]));
                pk.u[1] = pkbf(__builtin_amdgcn_exp2f(st[mi][2 * t][2]),
                               __builtin_amdgcn_exp2f(st[mi][2 * t][3]));
                pk.u[2] = pkbf(__builtin_amdgcn_exp2f(st[mi][2 * t + 1][0]),
                               __builtin_amdgcn_exp2f(st[mi][2 * t + 1][1]));
                pk.u[3] = pkbf(__builtin_amdgcn_exp2f(st[mi][2 * t + 1][2]),
                               __builtin_amdgcn_exp2f(st[mi][2 * t + 1][3]));
                bp[mi][t] = pk.v;
            }

        // O += P·V ; l += P·1  (virtual k: j<4 -> key 32t+quad*4+j,
        //                                  j>=4 -> key 32t+16+quad*4+j-4)
        #pragma unroll
        for (int t = 0; t < 2; ++t) {
            #pragma unroll
            for (int nd = 0; nd < 4; ++nd) {
                int d = nd * 16 + l16;
                s16x4 va = *(const s16x4*)&vcur[d * 64
                             + ((4 * t + (quad >> 1)) ^ (l16 & 7)) * 8
                             + (quad & 1) * 4];
                s16x4 vb = *(const s16x4*)&vcur[d * 64
                             + ((4 * t + 2 + (quad >> 1)) ^ (l16 & 7)) * 8
                             + (quad & 1) * 4];
                s16x8 av = {va[0], va[1], va[2], va[3],
                            vb[0], vb[1], vb[2], vb[3]};
                #pragma unroll
                for (int mi = 0; mi < 2; ++mi)
                    oacc[mi][nd] = __builtin_amdgcn_mfma_f32_16x16x32_bf16(
                        av, bp[mi][t], oacc[mi][nd], 0, 0, 0);
            }
            #pragma unroll
            for (int mi = 0; mi < 2; ++mi)
                lacc[mi] = __builtin_amdgcn_mfma_f32_16x16x32_bf16(
                    ones8, bp[mi][t], lacc[mi], 0, 0, 0);
        }
    }

    // partial store: unnormalized O (bf16, pkbf-packed) + l per row
    #pragma unroll
    for (int mi = 0; mi < 2; ++mi) {
        int srow = qb + w * 32 + mi * 16 + l16;
        long prow = (long)(z * 2 * NHD + bh) * SEQ + srow;
        if (quad == 0) lpart[prow] = lacc[mi][0];
        short* op = opart + prow * 64 + quad * 4;
        #pragma unroll
        for (int nd = 0; nd < 4; ++nd) {
            union { unsigned u[2]; s16x4 v; } pk;
            pk.u[0] = pkbf(oacc[mi][nd][0], oacc[mi][nd][1]);
            pk.u[1] = pkbf(oacc[mi][nd][2], oacc[mi][nd][3]);
            *(s16x4*)&op[nd * 16] = pk.v;
        }
    }
}

// ---------------- merge the two key-split partials -> att --------------------
__global__ __launch_bounds__(256)
void merge_k(const short* __restrict__ opart, const float* __restrict__ lpart,
             short* __restrict__ att) {
    int idx = blockIdx.x * 256 + threadIdx.x;     // 65536 rows x 16 thr/row
    int t16 = idx & 15, rowg = idx >> 4;
    int bh = rowg >> 11, srow = rowg & 2047;
    float inv = 1.0f / (lpart[rowg] + lpart[65536 + rowg]);
    s16x4 o1 = *(const s16x4*)&opart[(long)rowg * 64 + t16 * 4];
    s16x4 o2 = *(const s16x4*)&opart[(long)(65536 + rowg) * 64 + t16 * 4];
    int b = bh >> 4, h = bh & 15;
    short* dst = att + ((long)(b * SEQ + srow)) * HDIM + h * HD + t16 * 4;
    union { unsigned u[2]; s16x4 v; } r;
    r.u[0] = pkbf((bf2f(o1[0]) + bf2f(o2[0])) * inv,
                  (bf2f(o1[1]) + bf2f(o2[1])) * inv);
    r.u[1] = pkbf((bf2f(o1[2]) + bf2f(o2[2])) * inv,
                  (bf2f(o1[3]) + bf2f(o2[3])) * inv);
    *(s16x4*)dst = r.v;
}

// ---------------- projection GEMM: 64x128 tile, pure async16 staging ---------
// out[gm][n] = sum_col att[gm][col] * Wproj[n][col]. Grid 8x64 = 512 blocks
// = 2 blocks/CU (vs R15's 128-tile 1/CU); A staged via async16 (1 chunk/thr),
// B via async16 (2 chunks/thr). Double-buffered single-barrier K-loop.
__global__ __launch_bounds__(256, 2)
void gemm_proj(const short* __restrict__ A, const short* __restrict__ B,
               float* __restrict__ C) {
    __shared__ __align__(16) short As[2][64 * 32];
    __shared__ __align__(16) short Bs[2][128 * 32];
    const int tid  = threadIdx.x;
    const int w    = tid >> 6, lane = tid & 63;
    const int quad = lane >> 4, l16 = lane & 15;
    const int wm = (w >> 1) * 32, wn = (w & 1) * 64;
    const int rowA0 = blockIdx.y * 64;
    const int colB0 = blockIdx.x * 128;

    auto stage = [&](int buf, int kb) {
        {   // A: 64x32 = 256 chunks, 1 per thread
            int cidx = w * 64 + lane;
            int row = cidx >> 2, sc = cidx & 3;
            int c = sc ^ (row & 3);
            async16(&A[(long)(rowA0 + row) * HDIM + kb + c * 8],
                    &As[buf][(w * 64 + lane) * 8]);
        }
        #pragma unroll
        for (int i = 0; i < 2; ++i) {         // B: 128x32 = 512 chunks
            int cidx = i * 256 + w * 64 + lane;
            int row = cidx >> 2, sc = cidx & 3;
            int c = sc ^ (row & 3);
            async16(&B[(long)(colB0 + row) * HDIM + kb + c * 8],
                    &Bs[buf][(i * 256 + w * 64) * 8]);
        }
    };

    f32x4 acc[2][4] = {};
    stage(0, 0);

    for (int kb = 0, it = 0; kb < HDIM; kb += 32, ++it) {
        const int cur = it & 1;
        __syncthreads();                      // drains cur's loads; prev readers done
        if (kb + 32 < HDIM) stage(cur ^ 1, kb + 32);

        s16x8 af[2], bfr[4];
        const int slot = quad ^ (l16 & 3);
        #pragma unroll
        for (int mi = 0; mi < 2; ++mi)
            af[mi] = *(const s16x8*)&As[cur][(wm + mi * 16 + l16) * 32 + slot * 8];
        #pragma unroll
        for (int ni = 0; ni < 4; ++ni)
            bfr[ni] = *(const s16x8*)&Bs[cur][(wn + ni * 16 + l16) * 32 + slot * 8];
        #pragma unroll
        for (int mi = 0; mi < 2; ++mi)
            #pragma unroll
            for (int ni = 0; ni < 4; ++ni)
                acc[mi][ni] = __builtin_amdgcn_mfma_f32_16x16x32_bf16(
                    af[mi], bfr[ni], acc[mi][ni], 0, 0, 0);
    }

    const int cb = colB0 + wn;
    #pragma unroll
    for (int mi = 0; mi < 2; ++mi) {
        #pragma unroll
        for (int r = 0; r < 4; ++r) {
            int gm = rowA0 + wm + mi * 16 + quad * 4 + r;
            float* cp = C + (long)gm * HDIM + cb + l16;
            #pragma unroll
            for (int ni = 0; ni < 4; ++ni)
                cp[ni * 16] = acc[mi][ni][r];
        }
    }
}

extern "C" void kernel_launch(void* const* d_in, const int* in_sizes, int n_in,
                              void* d_out, int out_size, void* d_ws, size_t ws_size,
                              hipStream_t stream) {
    const void* x_raw  = d_in[0];
    const void* Wq_raw = d_in[1];
    const void* Wp_raw = d_in[2];
    for (int i = 0; i < n_in; ++i) {
        if      (in_sizes[i] == 4096 * 1024) x_raw  = d_in[i];  // [2,2048,1024]
        else if (in_sizes[i] == 3072 * 1024) Wq_raw = d_in[i];  // [3072,1024]
        else if (in_sizes[i] == 1024 * 1024) Wp_raw = d_in[i];  // [1024,1024]
    }
    float* out = (float*)d_out;               // [2,2048,1024] f32 output

    const size_t MB = 1u << 20;
    char* ws = (char*)d_ws;
    short*  q     = (short*)(ws);             // [2,16,2048,64]  8 MB (scaled)
    short*  k     = (short*)(ws +  8 * MB);   // [2,16,2048,64]  8 MB
    short*  vt    = (short*)(ws + 16 * MB);   // [2,16,64,2048]  8 MB (V^T)
    short*  xbf   = (short*)(ws + 24 * MB);   // [4096,1024]     8 MB (att reuses)
    short*  att   = xbf;                      // xbf consumed by gemm_qkv first
    short*  wqkv  = (short*)(ws + 32 * MB);   // [3072,1024]     6 MB
    short*  wprj  = (short*)(ws + 38 * MB);   // [1024,1024]     2 MB
    float2* tab   = (float2*)(ws + 40 * MB);  // [2048,32]       512 KB
    short*  opart = (short*)(ws + 41 * MB);   // 2 x [2,16,2048,64] 16 MB bf16
    float*  lprt  = (float*)(ws + 57 * MB);   // 2 x [2,16,2048]  512 KB

    cvt_rope_k<<<dim3(NCVT + SEQ * 32 / 256), dim3(256), 0, stream>>>(
        x_raw, Wq_raw, Wp_raw, xbf, wqkv, wprj, tab);

    gemm_qkv<<<dim3(3072 / 128, 4096 / 128), dim3(256), 0, stream>>>(
        xbf, wqkv, q, k, vt, tab, 1024);

    flash_attn<<<dim3(2 * NHD * 2, SEQ / 128), dim3(256), 0, stream>>>(
        q, k, vt, opart, lprt, 16);

    merge_k<<<dim3(65536 * 16 / 256), dim3(256), 0, stream>>>(opart, lprt, att);

    gemm_proj<<<dim3(1024 / 128, 4096 / 64), dim3(256), 0, stream>>>(
        att, wprj, out);
}